// Round 13
// baseline (219.385 us; speedup 1.0000x reference)
//
#include <hip/hip_runtime.h>
#include <hip/hip_bf16.h>
#include <stdint.h>

#define S_LEN 2048
#define DMODEL 1024
#define NH 16
#define HD 64
// scale: 1/sqrt(64) folded with log2(e) for v_exp_f32 (exp2)
#define SC2 0.18033688011112042f

typedef __attribute__((ext_vector_type(8))) short bf16x8;
typedef __attribute__((ext_vector_type(4))) float f32x4;
typedef unsigned long long u64;

__device__ __forceinline__ void gload16(const void* g, void* l) {
  __builtin_amdgcn_global_load_lds(
      reinterpret_cast<const __attribute__((address_space(1))) void*>(reinterpret_cast<uintptr_t>(g)),
      reinterpret_cast<__attribute__((address_space(3))) void*>(reinterpret_cast<uintptr_t>(l)),
      16, 0, 0);
}

__device__ __forceinline__ f32x4 mfma_bf16(bf16x8 a, bf16x8 b, f32x4 c) {
  return __builtin_amdgcn_mfma_f32_16x16x32_bf16(a, b, c, 0, 0, 0);
}

__device__ __forceinline__ unsigned short bfbits(float x) {
  __hip_bfloat16 h = __float2bfloat16(x);
  return *reinterpret_cast<unsigned short*>(&h);
}

__device__ __forceinline__ float asf(unsigned u) {
  union { unsigned u; float f; } c; c.u = u; return c.f;
}

// counted vmcnt + lgkm + barrier helpers (sched_barrier-fenced)
__device__ __forceinline__ void wait_vm0_bar() {
  __builtin_amdgcn_sched_barrier(0);
  asm volatile("s_waitcnt vmcnt(0) lgkmcnt(0)" ::: "memory");
  __builtin_amdgcn_s_barrier();
  __builtin_amdgcn_sched_barrier(0);
}
__device__ __forceinline__ void wait_vm2_bar() {
  __builtin_amdgcn_sched_barrier(0);
  asm volatile("s_waitcnt vmcnt(2) lgkmcnt(0)" ::: "memory");
  __builtin_amdgcn_s_barrier();
  __builtin_amdgcn_sched_barrier(0);
}
__device__ __forceinline__ void wait_vm4_bar() {
  __builtin_amdgcn_sched_barrier(0);
  asm volatile("s_waitcnt vmcnt(4) lgkmcnt(0)" ::: "memory");
  __builtin_amdgcn_s_barrier();
  __builtin_amdgcn_sched_barrier(0);
}

// ---------------- fused prep: convert ip f32->bf16  +  transpose 4 weight mats ----------------
__global__ __launch_bounds__(256) void k_prep(const float* __restrict__ ip,
                                              const float* __restrict__ wq,
                                              const float* __restrict__ wk,
                                              const float* __restrict__ wv,
                                              const float* __restrict__ fcw,
                                              __hip_bfloat16* __restrict__ ipb,
                                              __hip_bfloat16* __restrict__ wt_all,
                                              __hip_bfloat16* __restrict__ fct) {
  int bid = blockIdx.x;
  if (bid < 4096) {
    int i = (bid * 256 + threadIdx.x) * 4;
    f32x4 v = *(const f32x4*)(ip + i);
    u64 p = (u64)bfbits(v[0]) | ((u64)bfbits(v[1]) << 16) | ((u64)bfbits(v[2]) << 32)
          | ((u64)bfbits(v[3]) << 48);
    *reinterpret_cast<u64*>(ipb + i) = p;
    return;
  }
  bid -= 4096;
  const int z = bid >> 10, tile_id = bid & 1023;
  const float* src = (z == 0) ? wq : (z == 1) ? wk : (z == 2) ? wv : fcw;
  __hip_bfloat16* dst = (z == 3) ? fct : wt_all + (size_t)z * DMODEL * DMODEL;
  __shared__ float tile[32][33];
  const int nb = (tile_id & 31) * 32, kb = (tile_id >> 5) * 32;
  const int lx = threadIdx.x & 31, ly = threadIdx.x >> 5;  // 32x8
#pragma unroll
  for (int i = 0; i < 4; ++i)
    tile[ly + 8 * i][lx] = src[(size_t)(kb + ly + 8 * i) * DMODEL + nb + lx];
  __syncthreads();
#pragma unroll
  for (int i = 0; i < 4; ++i)
    dst[(size_t)(nb + ly + 8 * i) * DMODEL + kb + lx] = __float2bfloat16(tile[lx][ly + 8 * i]);
}

// ---------------- bf16 GEMM, 128x128 tile, BK=32, 4 waves (m97 structure) ----------------
// MODE 0: proj; writes Q/K [bh][s][64] bf16 and V TRANSPOSED: Vt [bh][64][s].
// MODE 1: fc; preln = acc + bias + residual(ipb bf16).
template <int MODE>
__global__ __launch_bounds__(256) void k_gemm(const __hip_bfloat16* __restrict__ A,
                                              const __hip_bfloat16* __restrict__ Bt,
                                              __hip_bfloat16* __restrict__ Q,
                                              __hip_bfloat16* __restrict__ Kk,
                                              __hip_bfloat16* __restrict__ Vt,
                                              const __hip_bfloat16* __restrict__ resid,
                                              const float* __restrict__ bias,
                                              float* __restrict__ preln) {
  __shared__ __align__(128) char lds[16384];
  char* Al = lds;
  char* Bl = lds + 8192;
  const int t = threadIdx.x;
  const int w = t >> 6, l = t & 63;
  const int g = l >> 4, lr = l & 15;
  const int cpx = gridDim.x >> 3;
  const int swz = (blockIdx.x & 7) * cpx + (blockIdx.x >> 3);
  const int bm = swz & 31;
  const int bn = swz >> 5;

  int sr0 = (w * 2 + 0) * 16 + (l >> 2);
  int sr1 = (w * 2 + 1) * 16 + (l >> 2);
  const int sc = (l & 3) * 16;
  const char* aSrc0 = (const char*)A + ((size_t)(bm * 128 + sr0)) * 2048 + (sc ^ (((sr0 >> 1) & 3) << 4));
  const char* aSrc1 = (const char*)A + ((size_t)(bm * 128 + sr1)) * 2048 + (sc ^ (((sr1 >> 1) & 3) << 4));
  const char* bSrc0 = (const char*)Bt + ((size_t)(bn * 128 + sr0)) * 2048 + (sc ^ (((sr0 >> 1) & 3) << 4));
  const char* bSrc1 = (const char*)Bt + ((size_t)(bn * 128 + sr1)) * 2048 + (sc ^ (((sr1 >> 1) & 3) << 4));

  const int wm = (w >> 1) * 64, wn = (w & 1) * 64;
  int roff[4], noff[4];
#pragma unroll
  for (int mi = 0; mi < 4; ++mi) {
    int m = wm + mi * 16 + lr;
    roff[mi] = m * 64 + ((g * 16) ^ (((m >> 1) & 3) << 4));
  }
#pragma unroll
  for (int ni = 0; ni < 4; ++ni) {
    int n = wn + ni * 16 + lr;
    noff[ni] = n * 64 + ((g * 16) ^ (((n >> 1) & 3) << 4));
  }

  f32x4 acc[4][4] = {};
  for (int k0 = 0; k0 < DMODEL; k0 += 32) {
    gload16(aSrc0 + k0 * 2, Al + (w * 2 + 0) * 1024);
    gload16(aSrc1 + k0 * 2, Al + (w * 2 + 1) * 1024);
    gload16(bSrc0 + k0 * 2, Bl + (w * 2 + 0) * 1024);
    gload16(bSrc1 + k0 * 2, Bl + (w * 2 + 1) * 1024);
    __syncthreads();
    bf16x8 af[4], bfv[4];
#pragma unroll
    for (int mi = 0; mi < 4; ++mi) af[mi] = *(const bf16x8*)(Al + roff[mi]);
#pragma unroll
    for (int ni = 0; ni < 4; ++ni) bfv[ni] = *(const bf16x8*)(Bl + noff[ni]);
#pragma unroll
    for (int mi = 0; mi < 4; ++mi)
#pragma unroll
      for (int ni = 0; ni < 4; ++ni)
        acc[mi][ni] = mfma_bf16(af[mi], bfv[ni], acc[mi][ni]);
    __syncthreads();
  }

#pragma unroll
  for (int mi = 0; mi < 4; ++mi)
#pragma unroll
    for (int ni = 0; ni < 4; ++ni) {
      f32x4 v = acc[mi][ni];
      const int m0 = bm * 128 + wm + mi * 16 + g * 4;
      const int n = bn * 128 + wn + ni * 16 + lr;
      if (MODE == 0) {
        const int mat = n >> 10, c = n & 1023;
        const int h = c >> 6, d = c & 63;
        const int b = m0 >> 11, s0 = m0 & 2047;
        if (mat == 2) {
          u64 p = (u64)bfbits(v[0]) | ((u64)bfbits(v[1]) << 16) | ((u64)bfbits(v[2]) << 32)
                | ((u64)bfbits(v[3]) << 48);
          *reinterpret_cast<u64*>(Vt + ((size_t)(b * NH + h) * HD + d) * S_LEN + s0) = p;
        } else {
          __hip_bfloat16* dst = (mat == 0) ? Q : Kk;
#pragma unroll
          for (int r = 0; r < 4; ++r)
            dst[(((size_t)(b * NH + h)) * S_LEN + s0 + r) * HD + d] = __float2bfloat16(v[r]);
        }
      } else {
#pragma unroll
        for (int r = 0; r < 4; ++r) {
          size_t idx = (size_t)(m0 + r) * DMODEL + n;
          preln[idx] = v[r] + bias[n] + __bfloat162float(resid[idx]);
        }
      }
    }
}

// ---------------- fused attention: persistent 2-item pipeline ----------------
// 512 blocks (2/CU, single resident generation) = 32 bh x 16 q-groups of 128
// rows (2 items x 64 q). Prologue: lsum sweep for item 0 (4-deep K ring).
// Main loop per item, per 64-kv chunk: stage K/V dbuf; stream lagged P group
// (G-1) as 2-row x 512B NT stores; QK^T(item) -> normalized P -> LDS group
// tile; QK^T(item+1) with the SAME staged K -> lsum_next (fuses the next
// item's pass 1 at ~zero staging cost -- kills the store-silent half of the
// kernel); PV; end-of-chunk s_waitcnt vmcnt(4) drains staging (FIFO-older)
// leaving this chunk's 4 stores in flight (R11 pacing). Store stream runs
// continuously across the item boundary via the lagged group index.
__global__ __launch_bounds__(256, 2) void k_attn10(const __hip_bfloat16* __restrict__ Q,
                                                   const __hip_bfloat16* __restrict__ K,
                                                   const __hip_bfloat16* __restrict__ Vt,
                                                   float* __restrict__ attn,
                                                   __hip_bfloat16* __restrict__ ctx) {
  __shared__ __align__(128) char KVst[4][8192];  // prologue: K 4-ring; main: K=[0..1], V=[2..3]
  __shared__ __align__(128) char Pw[2][4][4096]; // [G&1][wave][16q x 256B], swizzled

  const int t = threadIdx.x, w = t >> 6, l = t & 63;
  const int g = l >> 4, lr = l & 15;
  const int bid = blockIdx.x;              // 512 = 16 q-groups x 32 bh
  const int bh = bid & 31, qg = bid >> 5;  // all blocks of a bh land on XCD bh%8
  const int b = bh >> 4, h = bh & 15;
  const int qbase = qg * 128;
  const char* Kh = (const char*)(K + (size_t)bh * S_LEN * HD);
  const char* Vh = (const char*)(Vt + (size_t)bh * HD * S_LEN);
  const __hip_bfloat16* Qh = Q + (size_t)bh * S_LEN * HD;

  // Q fragments for both items (wave w owns rows [qbase+item*64+w*16, +16))
  bf16x8 qa0 = *(const bf16x8*)(Qh + (size_t)(qbase + w * 16 + lr) * HD + 8 * g);
  bf16x8 qa1 = *(const bf16x8*)(Qh + (size_t)(qbase + w * 16 + lr) * HD + 32 + 8 * g);
  bf16x8 qb0 = *(const bf16x8*)(Qh + (size_t)(qbase + 64 + w * 16 + lr) * HD + 8 * g);
  bf16x8 qb1 = *(const bf16x8*)(Qh + (size_t)(qbase + 64 + w * 16 + lr) * HD + 32 + 8 * g);

  // staging lane constants: LDS[row][sb] = G[row][sb ^ ((row&7)<<4)]
  const int srow0 = w * 8 + (l >> 3), srow1 = srow0 + 32;
  const int sbt = (l & 7) * 16;
  const int kso0 = srow0 * 128 + (sbt ^ ((srow0 & 7) << 4));
  const int kso1 = srow1 * 128 + (sbt ^ ((srow1 & 7) << 4));
  const int vso0 = srow0 * 4096 + (sbt ^ ((srow0 & 7) << 4));
  const int vso1 = srow1 * 4096 + (sbt ^ ((srow1 & 7) << 4));
  const int swz = (lr & 7) << 4;

  // ================= prologue: lsum for item 0 (4-deep staged K ring) =================
  gload16(Kh + kso0, &KVst[0][w * 1024]);
  gload16(Kh + kso1, &KVst[0][4096 + w * 1024]);
  gload16(Kh + 8192 + kso0, &KVst[1][w * 1024]);
  gload16(Kh + 8192 + kso1, &KVst[1][4096 + w * 1024]);
  float lsum = 0.f;
#define P1_COMPUTE(c)                                                                  \
  {                                                                                    \
    const char* kb_ = &KVst[(c) & 3][0];                                               \
    _Pragma("unroll") for (int st = 0; st < 4; ++st) {                                 \
      const char* kr = kb_ + (st * 16 + lr) * 128;                                     \
      bf16x8 kf0 = *(const bf16x8*)(kr + ((g * 16) ^ swz));                            \
      bf16x8 kf1 = *(const bf16x8*)(kr + ((64 + g * 16) ^ swz));                       \
      f32x4 s = {};                                                                    \
      s = mfma_bf16(kf0, qa0, s);                                                      \
      s = mfma_bf16(kf1, qa1, s);                                                      \
      lsum += __builtin_amdgcn_exp2f(s[0] * SC2) + __builtin_amdgcn_exp2f(s[1] * SC2)  \
            + __builtin_amdgcn_exp2f(s[2] * SC2) + __builtin_amdgcn_exp2f(s[3] * SC2); \
    }                                                                                  \
  }
  for (int c = 0; c < 30; ++c) {
    gload16(Kh + (c + 2) * 8192 + kso0, &KVst[(c + 2) & 3][w * 1024]);
    gload16(Kh + (c + 2) * 8192 + kso1, &KVst[(c + 2) & 3][4096 + w * 1024]);
    wait_vm4_bar();
    P1_COMPUTE(c);
  }
  wait_vm2_bar();
  P1_COMPUTE(30);
  wait_vm0_bar();
  P1_COMPUTE(31);
#undef P1_COMPUTE
  lsum += __shfl_xor(lsum, 16);
  lsum += __shfl_xor(lsum, 32);
  float inv = 1.0f / lsum;  // item 0, lane-resident (q == q-tile row lr)

  // ================= main: 2 items, pass2(i) + lsum(i+1) fused =================
  gload16(Kh + kso0, &KVst[0][w * 1024]);
  gload16(Kh + kso1, &KVst[0][4096 + w * 1024]);
  gload16(Vh + vso0, &KVst[2][w * 1024]);
  gload16(Vh + vso1, &KVst[2][4096 + w * 1024]);
  wait_vm0_bar();

  const int sl_row = l >> 5, sl_col = l & 31;
  float lsum_nxt = 0.f;
  f32x4 o[4] = {};

#pragma unroll
  for (int item = 0; item < 2; ++item) {
    const bf16x8 qc0 = item ? qb0 : qa0;
    const bf16x8 qc1 = item ? qb1 : qa1;
    const int q0 = qbase + item * 64 + w * 16;
    for (int c = 0; c < 32; ++c) {
      const int cur = c & 1;
      const int G = item * 16 + (c >> 1);  // group being produced
      const int gbuf = (c >> 1) & 1;
      const int ce = c & 1;
      const bool lastChunk = (item == 1) && (c == 31);
      if (!lastChunk) {
        const int cn = (c + 1) & 31;
        gload16(Kh + cn * 8192 + kso0, &KVst[cur ^ 1][w * 1024]);
        gload16(Kh + cn * 8192 + kso1, &KVst[cur ^ 1][4096 + w * 1024]);
        gload16(Vh + cn * 128 + vso0, &KVst[2 + (cur ^ 1)][w * 1024]);
        gload16(Vh + cn * 128 + vso1, &KVst[2 + (cur ^ 1)][4096 + w * 1024]);
      }
      // --- stream lagged group sg = G-1: 4 instrs x (2 rows x 512B), NT ---
      if (G >= 1) {
        const int sg = G - 1;
        const char* psrc = &Pw[sg & 1][w][0];
        const int kvb = (sg & 15) * 128;
        const size_t arowbase = ((size_t)bh * S_LEN + qbase + (sg >> 4) * 64 + w * 16) * S_LEN;
#pragma unroll
        for (int i = 0; i < 4; ++i) {
          int row = ce * 8 + 2 * i + sl_row;
          u64 v = *reinterpret_cast<const u64*>(psrc + row * 256 + ((sl_col * 8) ^ ((row & 7) << 4)));
          unsigned lo = (unsigned)v, hi = (unsigned)(v >> 32);
          f32x4 pv;
          pv[0] = asf(lo << 16);
          pv[1] = asf(lo & 0xffff0000u);
          pv[2] = asf(hi << 16);
          pv[3] = asf(hi & 0xffff0000u);
          __builtin_nontemporal_store(
              pv, (f32x4*)(attn + arowbase + (size_t)row * S_LEN + kvb + sl_col * 4));
        }
      }
      // --- QK^T(item) -> normalized P; QK^T(item+1) -> lsum_next (same kf regs) ---
#pragma unroll
      for (int st = 0; st < 4; ++st) {
        const char* kr = &KVst[cur][(st * 16 + lr) * 128];
        bf16x8 kf0 = *(const bf16x8*)(kr + ((g * 16) ^ swz));
        bf16x8 kf1 = *(const bf16x8*)(kr + ((64 + g * 16) ^ swz));
        f32x4 s = {};
        s = mfma_bf16(kf0, qc0, s);
        s = mfma_bf16(kf1, qc1, s);
        float p0 = __builtin_amdgcn_exp2f(s[0] * SC2) * inv;
        float p1 = __builtin_amdgcn_exp2f(s[1] * SC2) * inv;
        float p2 = __builtin_amdgcn_exp2f(s[2] * SC2) * inv;
        float p3 = __builtin_amdgcn_exp2f(s[3] * SC2) * inv;
        u64 u = (u64)bfbits(p0) | ((u64)bfbits(p1) << 16) | ((u64)bfbits(p2) << 32)
              | ((u64)bfbits(p3) << 48);
        *reinterpret_cast<u64*>(&Pw[gbuf][w][lr * 256 + ((ce * 128 + st * 32 + g * 8) ^ swz)]) = u;
        if (item == 0) {
          f32x4 sn = {};
          sn = mfma_bf16(kf0, qb0, sn);
          sn = mfma_bf16(kf1, qb1, sn);
          lsum_nxt += __builtin_amdgcn_exp2f(sn[0] * SC2) + __builtin_amdgcn_exp2f(sn[1] * SC2)
                    + __builtin_amdgcn_exp2f(sn[2] * SC2) + __builtin_amdgcn_exp2f(sn[3] * SC2);
        }
      }
      // --- PV (pure-MFMA cluster) ---
      __builtin_amdgcn_s_setprio(1);
#pragma unroll
      for (int ks = 0; ks < 2; ++ks) {
        bf16x8 pf = *(const bf16x8*)(&Pw[gbuf][w][lr * 256 + ((ce * 128 + ks * 64 + g * 16) ^ swz)]);
#pragma unroll
        for (int dvt = 0; dvt < 4; ++dvt) {
          const char* vb = &KVst[2 + cur][(dvt * 16 + lr) * 128];
          bf16x8 vf = *(const bf16x8*)(vb + ((ks * 64 + g * 16) ^ swz));
          o[dvt] = mfma_bf16(pf, vf, o[dvt]);
        }
      }
      __builtin_amdgcn_s_setprio(0);
      if (!lastChunk) wait_vm4_bar();  // drains staging (older), leaves 4 stores in flight
    }
    // --- per-item epilogue: ctx write (o normalized); prep inv for next item ---
#pragma unroll
    for (int dvt = 0; dvt < 4; ++dvt)
#pragma unroll
      for (int r = 0; r < 4; ++r) {
        int q = q0 + g * 4 + r;
        size_t idx = ((size_t)b * S_LEN + q) * DMODEL + h * HD + dvt * 16 + lr;
        ctx[idx] = __float2bfloat16(o[dvt][r]);
      }
    if (item == 0) {
      lsum_nxt += __shfl_xor(lsum_nxt, 16);
      lsum_nxt += __shfl_xor(lsum_nxt, 32);
      inv = 1.0f / lsum_nxt;
#pragma unroll
      for (int dvt = 0; dvt < 4; ++dvt) o[dvt] = f32x4{0.f, 0.f, 0.f, 0.f};
    }
  }

  // --- tail: stream group 31 (item 1, kv [1920,2048)) from Pw[1] ---
  {
    const char* psrc = &Pw[1][w][0];
    const size_t arowbase = ((size_t)bh * S_LEN + qbase + 64 + w * 16) * S_LEN;
#pragma unroll
    for (int i = 0; i < 8; ++i) {
      int row = 2 * i + sl_row;
      u64 v = *reinterpret_cast<const u64*>(psrc + row * 256 + ((sl_col * 8) ^ ((row & 7) << 4)));
      unsigned lo = (unsigned)v, hi = (unsigned)(v >> 32);
      f32x4 pv;
      pv[0] = asf(lo << 16);
      pv[1] = asf(lo & 0xffff0000u);
      pv[2] = asf(hi << 16);
      pv[3] = asf(hi & 0xffff0000u);
      __builtin_nontemporal_store(pv, (f32x4*)(attn + arowbase + (size_t)row * S_LEN + 1920 + sl_col * 4));
    }
  }
}

// ---------------- LayerNorm over rows of 1024 ----------------
__global__ __launch_bounds__(256) void k_ln(const float* __restrict__ x,
                                            const float* __restrict__ gam,
                                            const float* __restrict__ bet,
                                            float* __restrict__ y) {
  const int row = blockIdx.x;
  const int i = threadIdx.x * 4;
  const float* xr = x + (size_t)row * DMODEL;
  f32x4 v = *(const f32x4*)(xr + i);
  float s = v[0] + v[1] + v[2] + v[3];
  float s2 = v[0] * v[0] + v[1] * v[1] + v[2] * v[2] + v[3] * v[3];
#pragma unroll
  for (int off = 1; off < 64; off <<= 1) {
    s += __shfl_xor(s, off);
    s2 += __shfl_xor(s2, off);
  }
  __shared__ float red[2][4];
  const int w = threadIdx.x >> 6, ln = threadIdx.x & 63;
  if (ln == 0) { red[0][w] = s; red[1][w] = s2; }
  __syncthreads();
  s = red[0][0] + red[0][1] + red[0][2] + red[0][3];
  s2 = red[1][0] + red[1][1] + red[1][2] + red[1][3];
  const float mu = s * (1.f / DMODEL);
  const float rstd = rsqrtf(s2 * (1.f / DMODEL) - mu * mu + 1e-6f);
  f32x4 gv = *(const f32x4*)(gam + i), bv = *(const f32x4*)(bet + i);
  f32x4 out;
#pragma unroll
  for (int j = 0; j < 4; ++j) out[j] = (v[j] - mu) * rstd * gv[j] + bv[j];
  *(f32x4*)(y + (size_t)row * DMODEL + i) = out;
}

extern "C" void kernel_launch(void* const* d_in, const int* in_sizes, int n_in,
                              void* d_out, int out_size, void* d_ws, size_t ws_size,
                              hipStream_t stream) {
  const float* ip  = (const float*)d_in[0];
  const float* wk  = (const float*)d_in[1];
  const float* wq  = (const float*)d_in[2];
  const float* wv  = (const float*)d_in[3];
  const float* fcw = (const float*)d_in[4];
  const float* fcb = (const float*)d_in[5];
  const float* lng = (const float*)d_in[6];
  const float* lnb = (const float*)d_in[7];

  float* y = (float*)d_out;
  float* attn = y + (size_t)2 * S_LEN * DMODEL;  // outputs concatenated (y, attn)

  char* ws = (char*)d_ws;
  __hip_bfloat16* ipb = (__hip_bfloat16*)(ws);                  //  8 MB: ip bf16
  __hip_bfloat16* wt  = (__hip_bfloat16*)(ws + (8ll << 20));    //  6 MB: [wq^T|wk^T|wv^T]
  __hip_bfloat16* fct = (__hip_bfloat16*)(ws + (14ll << 20));   //  2 MB: fc_w^T
  __hip_bfloat16* Qb  = (__hip_bfloat16*)(ws + (16ll << 20));   //  8 MB: Q [32 bh][2048][64]
  __hip_bfloat16* Kb  = (__hip_bfloat16*)(ws + (24ll << 20));   //  8 MB: K
  __hip_bfloat16* Vtb = (__hip_bfloat16*)(ws + (40ll << 20));   //  8 MB: V^T [32 bh][64][2048]
  __hip_bfloat16* ctx = (__hip_bfloat16*)(ws + (48ll << 20));   //  8 MB: ctx
  float* preln        = (float*)(ws + (56ll << 20));            // 16 MB: pre-LN f32

  k_prep<<<8192, 256, 0, stream>>>(ip, wq, wk, wv, fcw, ipb, wt, fct);
  k_gemm<0><<<32 * 24, 256, 0, stream>>>(ipb, wt, Qb, Kb, Vtb, nullptr, nullptr, nullptr);
  k_attn10<<<512, 256, 0, stream>>>(Qb, Kb, Vtb, attn, ctx);
  k_gemm<1><<<32 * 8, 256, 0, stream>>>(ctx, fct, nullptr, nullptr, nullptr, ipb, fcb, preln);
  k_ln<<<4096, 256, 0, stream>>>(preln, lng, lnb, y);
}

// Round 14
// 211.542 us; speedup vs baseline: 1.0371x; 1.0371x over previous
//
#include <hip/hip_runtime.h>
#include <hip/hip_bf16.h>
#include <stdint.h>

#define S_LEN 2048
#define DMODEL 1024
#define NH 16
#define HD 64
// scale: 1/sqrt(64) folded with log2(e) for v_exp_f32 (exp2)
#define SC2 0.18033688011112042f

typedef __attribute__((ext_vector_type(8))) short bf16x8;
typedef __attribute__((ext_vector_type(4))) float f32x4;
typedef unsigned long long u64;

__device__ __forceinline__ void gload16(const void* g, void* l) {
  __builtin_amdgcn_global_load_lds(
      reinterpret_cast<const __attribute__((address_space(1))) void*>(reinterpret_cast<uintptr_t>(g)),
      reinterpret_cast<__attribute__((address_space(3))) void*>(reinterpret_cast<uintptr_t>(l)),
      16, 0, 0);
}

__device__ __forceinline__ f32x4 mfma_bf16(bf16x8 a, bf16x8 b, f32x4 c) {
  return __builtin_amdgcn_mfma_f32_16x16x32_bf16(a, b, c, 0, 0, 0);
}

__device__ __forceinline__ unsigned short bfbits(float x) {
  __hip_bfloat16 h = __float2bfloat16(x);
  return *reinterpret_cast<unsigned short*>(&h);
}

__device__ __forceinline__ float asf(unsigned u) {
  union { unsigned u; float f; } c; c.u = u; return c.f;
}

// counted vmcnt + lgkm + barrier helpers (sched_barrier-fenced)
__device__ __forceinline__ void wait_vm0_bar() {
  __builtin_amdgcn_sched_barrier(0);
  asm volatile("s_waitcnt vmcnt(0) lgkmcnt(0)" ::: "memory");
  __builtin_amdgcn_s_barrier();
  __builtin_amdgcn_sched_barrier(0);
}
__device__ __forceinline__ void wait_vm2_bar() {
  __builtin_amdgcn_sched_barrier(0);
  asm volatile("s_waitcnt vmcnt(2) lgkmcnt(0)" ::: "memory");
  __builtin_amdgcn_s_barrier();
  __builtin_amdgcn_sched_barrier(0);
}
__device__ __forceinline__ void wait_vm4_bar() {
  __builtin_amdgcn_sched_barrier(0);
  asm volatile("s_waitcnt vmcnt(4) lgkmcnt(0)" ::: "memory");
  __builtin_amdgcn_s_barrier();
  __builtin_amdgcn_sched_barrier(0);
}

// ---------------- fused prep: convert ip f32->bf16  +  transpose 4 weight mats ----------------
__global__ __launch_bounds__(256) void k_prep(const float* __restrict__ ip,
                                              const float* __restrict__ wq,
                                              const float* __restrict__ wk,
                                              const float* __restrict__ wv,
                                              const float* __restrict__ fcw,
                                              __hip_bfloat16* __restrict__ ipb,
                                              __hip_bfloat16* __restrict__ wt_all,
                                              __hip_bfloat16* __restrict__ fct) {
  int bid = blockIdx.x;
  if (bid < 4096) {
    int i = (bid * 256 + threadIdx.x) * 4;
    f32x4 v = *(const f32x4*)(ip + i);
    u64 p = (u64)bfbits(v[0]) | ((u64)bfbits(v[1]) << 16) | ((u64)bfbits(v[2]) << 32)
          | ((u64)bfbits(v[3]) << 48);
    *reinterpret_cast<u64*>(ipb + i) = p;
    return;
  }
  bid -= 4096;
  const int z = bid >> 10, tile_id = bid & 1023;
  const float* src = (z == 0) ? wq : (z == 1) ? wk : (z == 2) ? wv : fcw;
  __hip_bfloat16* dst = (z == 3) ? fct : wt_all + (size_t)z * DMODEL * DMODEL;
  __shared__ float tile[32][33];
  const int nb = (tile_id & 31) * 32, kb = (tile_id >> 5) * 32;
  const int lx = threadIdx.x & 31, ly = threadIdx.x >> 5;  // 32x8
#pragma unroll
  for (int i = 0; i < 4; ++i)
    tile[ly + 8 * i][lx] = src[(size_t)(kb + ly + 8 * i) * DMODEL + nb + lx];
  __syncthreads();
#pragma unroll
  for (int i = 0; i < 4; ++i)
    dst[(size_t)(nb + ly + 8 * i) * DMODEL + kb + lx] = __float2bfloat16(tile[lx][ly + 8 * i]);
}

// ---------------- bf16 GEMM, 128x128 tile, BK=32, 4 waves (m97 structure) ----------------
// MODE 0: proj; writes Q/K [bh][s][64] bf16 and V TRANSPOSED: Vt [bh][64][s].
// MODE 1: fc; preln = acc + bias + residual(ipb bf16).
template <int MODE>
__global__ __launch_bounds__(256) void k_gemm(const __hip_bfloat16* __restrict__ A,
                                              const __hip_bfloat16* __restrict__ Bt,
                                              __hip_bfloat16* __restrict__ Q,
                                              __hip_bfloat16* __restrict__ Kk,
                                              __hip_bfloat16* __restrict__ Vt,
                                              const __hip_bfloat16* __restrict__ resid,
                                              const float* __restrict__ bias,
                                              float* __restrict__ preln) {
  __shared__ __align__(128) char lds[16384];
  char* Al = lds;
  char* Bl = lds + 8192;
  const int t = threadIdx.x;
  const int w = t >> 6, l = t & 63;
  const int g = l >> 4, lr = l & 15;
  const int cpx = gridDim.x >> 3;
  const int swz = (blockIdx.x & 7) * cpx + (blockIdx.x >> 3);
  const int bm = swz & 31;
  const int bn = swz >> 5;

  int sr0 = (w * 2 + 0) * 16 + (l >> 2);
  int sr1 = (w * 2 + 1) * 16 + (l >> 2);
  const int sc = (l & 3) * 16;
  const char* aSrc0 = (const char*)A + ((size_t)(bm * 128 + sr0)) * 2048 + (sc ^ (((sr0 >> 1) & 3) << 4));
  const char* aSrc1 = (const char*)A + ((size_t)(bm * 128 + sr1)) * 2048 + (sc ^ (((sr1 >> 1) & 3) << 4));
  const char* bSrc0 = (const char*)Bt + ((size_t)(bn * 128 + sr0)) * 2048 + (sc ^ (((sr0 >> 1) & 3) << 4));
  const char* bSrc1 = (const char*)Bt + ((size_t)(bn * 128 + sr1)) * 2048 + (sc ^ (((sr1 >> 1) & 3) << 4));

  const int wm = (w >> 1) * 64, wn = (w & 1) * 64;
  int roff[4], noff[4];
#pragma unroll
  for (int mi = 0; mi < 4; ++mi) {
    int m = wm + mi * 16 + lr;
    roff[mi] = m * 64 + ((g * 16) ^ (((m >> 1) & 3) << 4));
  }
#pragma unroll
  for (int ni = 0; ni < 4; ++ni) {
    int n = wn + ni * 16 + lr;
    noff[ni] = n * 64 + ((g * 16) ^ (((n >> 1) & 3) << 4));
  }

  f32x4 acc[4][4] = {};
  for (int k0 = 0; k0 < DMODEL; k0 += 32) {
    gload16(aSrc0 + k0 * 2, Al + (w * 2 + 0) * 1024);
    gload16(aSrc1 + k0 * 2, Al + (w * 2 + 1) * 1024);
    gload16(bSrc0 + k0 * 2, Bl + (w * 2 + 0) * 1024);
    gload16(bSrc1 + k0 * 2, Bl + (w * 2 + 1) * 1024);
    __syncthreads();
    bf16x8 af[4], bfv[4];
#pragma unroll
    for (int mi = 0; mi < 4; ++mi) af[mi] = *(const bf16x8*)(Al + roff[mi]);
#pragma unroll
    for (int ni = 0; ni < 4; ++ni) bfv[ni] = *(const bf16x8*)(Bl + noff[ni]);
#pragma unroll
    for (int mi = 0; mi < 4; ++mi)
#pragma unroll
      for (int ni = 0; ni < 4; ++ni)
        acc[mi][ni] = mfma_bf16(af[mi], bfv[ni], acc[mi][ni]);
    __syncthreads();
  }

#pragma unroll
  for (int mi = 0; mi < 4; ++mi)
#pragma unroll
    for (int ni = 0; ni < 4; ++ni) {
      f32x4 v = acc[mi][ni];
      const int m0 = bm * 128 + wm + mi * 16 + g * 4;
      const int n = bn * 128 + wn + ni * 16 + lr;
      if (MODE == 0) {
        const int mat = n >> 10, c = n & 1023;
        const int h = c >> 6, d = c & 63;
        const int b = m0 >> 11, s0 = m0 & 2047;
        if (mat == 2) {
          u64 p = (u64)bfbits(v[0]) | ((u64)bfbits(v[1]) << 16) | ((u64)bfbits(v[2]) << 32)
                | ((u64)bfbits(v[3]) << 48);
          *reinterpret_cast<u64*>(Vt + ((size_t)(b * NH + h) * HD + d) * S_LEN + s0) = p;
        } else {
          __hip_bfloat16* dst = (mat == 0) ? Q : Kk;
#pragma unroll
          for (int r = 0; r < 4; ++r)
            dst[(((size_t)(b * NH + h)) * S_LEN + s0 + r) * HD + d] = __float2bfloat16(v[r]);
        }
      } else {
#pragma unroll
        for (int r = 0; r < 4; ++r) {
          size_t idx = (size_t)(m0 + r) * DMODEL + n;
          preln[idx] = v[r] + bias[n] + __bfloat162float(resid[idx]);
        }
      }
    }
}

// ---------------- fused attention: staged 2-pass, LDS-transposed coalesced attn streams ----
// (R11 champion: counted-vmcnt staging schedule + 2-row x 512B NT streams + setprio.)
__global__ __launch_bounds__(256, 2) void k_attn8(const __hip_bfloat16* __restrict__ Q,
                                                  const __hip_bfloat16* __restrict__ K,
                                                  const __hip_bfloat16* __restrict__ Vt,
                                                  float* __restrict__ attn,
                                                  __hip_bfloat16* __restrict__ ctx) {
  __shared__ __align__(128) char KVst[4][8192];  // pass1: K 4-ring; pass2: K=[0..1], V=[2..3]
  __shared__ __align__(128) char Pw[2][4][4096]; // [groupbuf][wave][16q x 256B], swizzled

  const int t = threadIdx.x, w = t >> 6, l = t & 63;
  const int g = l >> 4, lr = l & 15;
  const int bid = blockIdx.x;              // 1024 = 32 q-tiles x 32 bh
  const int bh = bid & 31, qi = bid >> 5;  // all blocks of a bh land on XCD bh%8
  const int b = bh >> 4, h = bh & 15;
  const int q0 = qi * 64 + w * 16;
  const char* Kh = (const char*)(K + (size_t)bh * S_LEN * HD);
  const char* Vh = (const char*)(Vt + (size_t)bh * HD * S_LEN);
  const __hip_bfloat16* Qh = Q + (size_t)bh * S_LEN * HD;

  bf16x8 qf0 = *(const bf16x8*)(Qh + (size_t)(q0 + lr) * HD + 8 * g);
  bf16x8 qf1 = *(const bf16x8*)(Qh + (size_t)(q0 + lr) * HD + 32 + 8 * g);

  // staging lane constants: LDS[row][sb] = G[row][sb ^ ((row&7)<<4)]
  const int srow0 = w * 8 + (l >> 3), srow1 = srow0 + 32;
  const int sb = (l & 7) * 16;
  const int kso0 = srow0 * 128 + (sb ^ ((srow0 & 7) << 4));
  const int kso1 = srow1 * 128 + (sb ^ ((srow1 & 7) << 4));
  const int vso0 = srow0 * 4096 + (sb ^ ((srow0 & 7) << 4));
  const int vso1 = srow1 * 4096 + (sb ^ ((srow1 & 7) << 4));
  const int swz = (lr & 7) << 4;

  // ================= pass 1: row sums (4-deep staged K pipeline) =================
  gload16(Kh + kso0, &KVst[0][w * 1024]);
  gload16(Kh + kso1, &KVst[0][4096 + w * 1024]);
  gload16(Kh + 8192 + kso0, &KVst[1][w * 1024]);
  gload16(Kh + 8192 + kso1, &KVst[1][4096 + w * 1024]);
  float lsum = 0.f;
#define P1_COMPUTE(c)                                                              \
  {                                                                                \
    const char* kb_ = &KVst[(c) & 3][0];                                           \
    _Pragma("unroll") for (int st = 0; st < 4; ++st) {                             \
      const char* kr = kb_ + (st * 16 + lr) * 128;                                 \
      bf16x8 kf0 = *(const bf16x8*)(kr + ((g * 16) ^ swz));                        \
      bf16x8 kf1 = *(const bf16x8*)(kr + ((64 + g * 16) ^ swz));                   \
      f32x4 s = {};                                                                \
      s = mfma_bf16(kf0, qf0, s);                                                  \
      s = mfma_bf16(kf1, qf1, s);                                                  \
      lsum += __builtin_amdgcn_exp2f(s[0] * SC2) + __builtin_amdgcn_exp2f(s[1] * SC2) \
            + __builtin_amdgcn_exp2f(s[2] * SC2) + __builtin_amdgcn_exp2f(s[3] * SC2); \
    }                                                                              \
  }
  for (int c = 0; c < 30; ++c) {
    gload16(Kh + (c + 2) * 8192 + kso0, &KVst[(c + 2) & 3][w * 1024]);
    gload16(Kh + (c + 2) * 8192 + kso1, &KVst[(c + 2) & 3][4096 + w * 1024]);
    wait_vm4_bar();
    P1_COMPUTE(c);
  }
  wait_vm2_bar();
  P1_COMPUTE(30);
  wait_vm0_bar();
  P1_COMPUTE(31);
#undef P1_COMPUTE
  lsum += __shfl_xor(lsum, 16);
  lsum += __shfl_xor(lsum, 32);
  const float inv = 1.0f / lsum;  // lane-resident: this lane's q == q0+lr

  // ================= pass 2 =================
  gload16(Kh + kso0, &KVst[0][w * 1024]);
  gload16(Kh + kso1, &KVst[0][4096 + w * 1024]);
  gload16(Vh + vso0, &KVst[2][w * 1024]);
  gload16(Vh + vso1, &KVst[2][4096 + w * 1024]);
  wait_vm0_bar();  // also pass1 -> pass2 rendezvous

  f32x4 o[4] = {};
  const size_t arowbase = ((size_t)bh * S_LEN + q0) * S_LEN;  // + row*S_LEN + col
  const int sl_row = l >> 5, sl_col = l & 31;  // stream lane mapping
  for (int c = 0; c < 32; ++c) {
    const int cur = c & 1;          // K/V staging buffer
    const int gbuf = (c >> 1) & 1;  // P group buffer
    const int ce = c & 1;           // chunk parity within group
    if (c < 31) {
      gload16(Kh + (c + 1) * 8192 + kso0, &KVst[cur ^ 1][w * 1024]);
      gload16(Kh + (c + 1) * 8192 + kso1, &KVst[cur ^ 1][4096 + w * 1024]);
      gload16(Vh + (c + 1) * 128 + vso0, &KVst[2 + (cur ^ 1)][w * 1024]);
      gload16(Vh + (c + 1) * 128 + vso1, &KVst[2 + (cur ^ 1)][4096 + w * 1024]);
    }
    // --- stream prev group (if any): 4 instrs x (2 rows x 512B), NT, contiguous ---
    if (c >= 2) {
      const char* psrc = &Pw[gbuf ^ 1][w][0];
      const int kvb = ((c >> 1) - 1) * 128;
#pragma unroll
      for (int i = 0; i < 4; ++i) {
        int row = ce * 8 + 2 * i + sl_row;
        u64 v = *reinterpret_cast<const u64*>(psrc + row * 256 + ((sl_col * 8) ^ ((row & 7) << 4)));
        unsigned lo = (unsigned)v, hi = (unsigned)(v >> 32);
        f32x4 pv;
        pv[0] = asf(lo << 16);
        pv[1] = asf(lo & 0xffff0000u);
        pv[2] = asf(hi << 16);
        pv[3] = asf(hi & 0xffff0000u);
        __builtin_nontemporal_store(pv, (f32x4*)(attn + arowbase + (size_t)row * S_LEN + kvb + sl_col * 4));
      }
    }
    // --- QK^T + exp + normalized P -> LDS group tile ---
#pragma unroll
    for (int st = 0; st < 4; ++st) {
      const char* kr = &KVst[cur][(st * 16 + lr) * 128];
      bf16x8 kf0 = *(const bf16x8*)(kr + ((g * 16) ^ swz));
      bf16x8 kf1 = *(const bf16x8*)(kr + ((64 + g * 16) ^ swz));
      f32x4 s = {};
      s = mfma_bf16(kf0, qf0, s);
      s = mfma_bf16(kf1, qf1, s);
      float p0 = __builtin_amdgcn_exp2f(s[0] * SC2) * inv;
      float p1 = __builtin_amdgcn_exp2f(s[1] * SC2) * inv;
      float p2 = __builtin_amdgcn_exp2f(s[2] * SC2) * inv;
      float p3 = __builtin_amdgcn_exp2f(s[3] * SC2) * inv;
      u64 u = (u64)bfbits(p0) | ((u64)bfbits(p1) << 16) | ((u64)bfbits(p2) << 32)
            | ((u64)bfbits(p3) << 48);
      *reinterpret_cast<u64*>(&Pw[gbuf][w][lr * 256 + ((ce * 128 + st * 32 + g * 8) ^ swz)]) = u;
    }
    // --- PV from this chunk's P half (pure-MFMA cluster: setprio) ---
    __builtin_amdgcn_s_setprio(1);
#pragma unroll
    for (int ks = 0; ks < 2; ++ks) {
      bf16x8 pf = *(const bf16x8*)(&Pw[gbuf][w][lr * 256 + ((ce * 128 + ks * 64 + g * 16) ^ swz)]);
#pragma unroll
      for (int dvt = 0; dvt < 4; ++dvt) {
        const char* vb = &KVst[2 + cur][(dvt * 16 + lr) * 128];
        bf16x8 vf = *(const bf16x8*)(vb + ((ks * 64 + g * 16) ^ swz));
        o[dvt] = mfma_bf16(pf, vf, o[dvt]);
      }
    }
    __builtin_amdgcn_s_setprio(0);
    if (c < 31) wait_vm4_bar();  // drains staging (older), leaves this chunk's 4 stores
  }

  // --- tail: stream group 15 (kv [1920,2048)), 8 instrs ---
  {
    const char* psrc = &Pw[1][w][0];
#pragma unroll
    for (int i = 0; i < 8; ++i) {
      int row = 2 * i + sl_row;
      u64 v = *reinterpret_cast<const u64*>(psrc + row * 256 + ((sl_col * 8) ^ ((row & 7) << 4)));
      unsigned lo = (unsigned)v, hi = (unsigned)(v >> 32);
      f32x4 pv;
      pv[0] = asf(lo << 16);
      pv[1] = asf(lo & 0xffff0000u);
      pv[2] = asf(hi << 16);
      pv[3] = asf(hi & 0xffff0000u);
      __builtin_nontemporal_store(pv, (f32x4*)(attn + arowbase + (size_t)row * S_LEN + 1920 + sl_col * 4));
    }
  }

  // epilogue: ctx[(b,q)][h*64+dv], q = q0 + 4g + r, d-col = lr (o already normalized)
#pragma unroll
  for (int dvt = 0; dvt < 4; ++dvt)
#pragma unroll
    for (int r = 0; r < 4; ++r) {
      int q = q0 + g * 4 + r;
      size_t idx = ((size_t)b * S_LEN + q) * DMODEL + h * HD + dvt * 16 + lr;
      ctx[idx] = __float2bfloat16(o[dvt][r]);
    }
}

// ---------------- LayerNorm over rows of 1024 ----------------
__global__ __launch_bounds__(256) void k_ln(const float* __restrict__ x,
                                            const float* __restrict__ gam,
                                            const float* __restrict__ bet,
                                            float* __restrict__ y) {
  const int row = blockIdx.x;
  const int i = threadIdx.x * 4;
  const float* xr = x + (size_t)row * DMODEL;
  f32x4 v = *(const f32x4*)(xr + i);
  float s = v[0] + v[1] + v[2] + v[3];
  float s2 = v[0] * v[0] + v[1] * v[1] + v[2] * v[2] + v[3] * v[3];
#pragma unroll
  for (int off = 1; off < 64; off <<= 1) {
    s += __shfl_xor(s, off);
    s2 += __shfl_xor(s2, off);
  }
  __shared__ float red[2][4];
  const int w = threadIdx.x >> 6, ln = threadIdx.x & 63;
  if (ln == 0) { red[0][w] = s; red[1][w] = s2; }
  __syncthreads();
  s = red[0][0] + red[0][1] + red[0][2] + red[0][3];
  s2 = red[1][0] + red[1][1] + red[1][2] + red[1][3];
  const float mu = s * (1.f / DMODEL);
  const float rstd = rsqrtf(s2 * (1.f / DMODEL) - mu * mu + 1e-6f);
  f32x4 gv = *(const f32x4*)(gam + i), bv = *(const f32x4*)(bet + i);
  f32x4 out;
#pragma unroll
  for (int j = 0; j < 4; ++j) out[j] = (v[j] - mu) * rstd * gv[j] + bv[j];
  *(f32x4*)(y + (size_t)row * DMODEL + i) = out;
}

extern "C" void kernel_launch(void* const* d_in, const int* in_sizes, int n_in,
                              void* d_out, int out_size, void* d_ws, size_t ws_size,
                              hipStream_t stream) {
  const float* ip  = (const float*)d_in[0];
  const float* wk  = (const float*)d_in[1];
  const float* wq  = (const float*)d_in[2];
  const float* wv  = (const float*)d_in[3];
  const float* fcw = (const float*)d_in[4];
  const float* fcb = (const float*)d_in[5];
  const float* lng = (const float*)d_in[6];
  const float* lnb = (const float*)d_in[7];

  float* y = (float*)d_out;
  float* attn = y + (size_t)2 * S_LEN * DMODEL;  // outputs concatenated (y, attn)

  char* ws = (char*)d_ws;
  __hip_bfloat16* ipb = (__hip_bfloat16*)(ws);                  //  8 MB: ip bf16
  __hip_bfloat16* wt  = (__hip_bfloat16*)(ws + (8ll << 20));    //  6 MB: [wq^T|wk^T|wv^T]
  __hip_bfloat16* fct = (__hip_bfloat16*)(ws + (14ll << 20));   //  2 MB: fc_w^T
  __hip_bfloat16* Qb  = (__hip_bfloat16*)(ws + (16ll << 20));   //  8 MB: Q [32 bh][2048][64]
  __hip_bfloat16* Kb  = (__hip_bfloat16*)(ws + (24ll << 20));   //  8 MB: K
  __hip_bfloat16* Vtb = (__hip_bfloat16*)(ws + (40ll << 20));   //  8 MB: V^T [32 bh][64][2048]
  __hip_bfloat16* ctx = (__hip_bfloat16*)(ws + (48ll << 20));   //  8 MB: ctx
  float* preln        = (float*)(ws + (56ll << 20));            // 16 MB: pre-LN f32

  k_prep<<<8192, 256, 0, stream>>>(ip, wq, wk, wv, fcw, ipb, wt, fct);
  k_gemm<0><<<32 * 24, 256, 0, stream>>>(ipb, wt, Qb, Kb, Vtb, nullptr, nullptr, nullptr);
  k_attn8<<<1024, 256, 0, stream>>>(Qb, Kb, Vtb, attn, ctx);
  k_gemm<1><<<32 * 8, 256, 0, stream>>>(ctx, fct, nullptr, nullptr, nullptr, ipb, fcb, preln);
  k_ln<<<4096, 256, 0, stream>>>(preln, lng, lnb, y);
}